// Round 1
// baseline (3275.164 us; speedup 1.0000x reference)
//
#include <hip/hip_runtime.h>
#include <math.h>

#define NB   64
#define SS   96
#define EE   300
#define DD   512
#define HH   256
#define SELD 128
#define CK   1280   // 5*H
#define MLPD 1024
#define NCLS 3

// ---------------- transpose kernels: W[e][k] -> W4[e4][k] (float4 of 4 consecutive e) -------------
__global__ void k_trans_comp(const float* __restrict__ Wc, float* __restrict__ Wc4) {
    int e4 = blockIdx.x;            // 0..127
    for (int i = 0; i < 5; i++) {
        int k = threadIdx.x + 256 * i;
        float4 v;
        v.x = Wc[(4 * e4 + 0) * CK + k];
        v.y = Wc[(4 * e4 + 1) * CK + k];
        v.z = Wc[(4 * e4 + 2) * CK + k];
        v.w = Wc[(4 * e4 + 3) * CK + k];
        ((float4*)Wc4)[e4 * CK + k] = v;
    }
}

__global__ void k_trans_sel(const float* __restrict__ Ws, float* __restrict__ Ws4) {
    int e4 = blockIdx.x;            // 0..127
    int k = threadIdx.x;            // 0..127
    float4 v;
    v.x = Ws[(4 * e4 + 0) * SELD + k];
    v.y = Ws[(4 * e4 + 1) * SELD + k];
    v.z = Ws[(4 * e4 + 2) * SELD + k];
    v.w = Ws[(4 * e4 + 3) * SELD + k];
    ((float4*)Ws4)[e4 * SELD + k] = v;
}

// ---------------- encode: states[b][s][:] = emb[sent[b][s]] @ W_enc + b_enc ----------------------
__global__ __launch_bounds__(512) void k_encode(const int* __restrict__ sent,
                                                const float* __restrict__ emb,
                                                const float* __restrict__ Wenc,
                                                const float* __restrict__ benc,
                                                float* __restrict__ state) {
    int b = blockIdx.x / 3, tile = blockIdx.x % 3, s0 = tile * 32;
    __shared__ int tok[32];
    __shared__ __align__(16) float elds[32 * 300];
    int tid = threadIdx.x;
    if (tid < 32) tok[tid] = sent[b * SS + s0 + tid];
    __syncthreads();
    for (int i = tid; i < 32 * 300; i += 512) {
        int s = i / 300, e = i - s * 300;
        elds[i] = emb[(long)tok[s] * EE + e];
    }
    __syncthreads();
    int d = tid;
    float bv = benc[d];
    float acc[32];
#pragma unroll
    for (int s = 0; s < 32; s++) acc[s] = bv;
    for (int e4 = 0; e4 < 75; e4++) {
        float w0 = Wenc[(4 * e4 + 0) * DD + d];
        float w1 = Wenc[(4 * e4 + 1) * DD + d];
        float w2 = Wenc[(4 * e4 + 2) * DD + d];
        float w3 = Wenc[(4 * e4 + 3) * DD + d];
#pragma unroll
        for (int s = 0; s < 32; s++) {
            float4 x = *(const float4*)&elds[s * 300 + 4 * e4];
            acc[s] += x.x * w0 + x.y * w1 + x.z * w2 + x.w * w3;
        }
    }
    for (int s = 0; s < 32; s++)
        state[(b * SS + s0 + s) * DD + d] = acc[s];
}

// ---------------- initial logits for all 95 pairs per batch -------------------------------------
__global__ __launch_bounds__(128) void k_logits0(const float* __restrict__ state,
                                                 const float* __restrict__ Ws4,
                                                 const float* __restrict__ bs1,
                                                 const float* __restrict__ Ws2,
                                                 const float* __restrict__ bs2,
                                                 float* __restrict__ log0) {
    int b = blockIdx.x / 5, tile = blockIdx.x % 5, p0 = tile * 19;
    __shared__ __align__(16) float hl[20 * 256];     // h rows p0..p0+19
    __shared__ float part[2][19];
    int tid = threadIdx.x;
    for (int i = tid; i < 20 * 256; i += 128) {
        int r = i >> 8, c = i & 255;
        hl[i] = state[(b * SS + p0 + r) * DD + HH + c];
    }
    __syncthreads();
    int k = tid;
    float acc[19];
#pragma unroll
    for (int p = 0; p < 19; p++) acc[p] = 0.f;
    const float4* W4 = (const float4*)Ws4;
    const float4* h4 = (const float4*)hl;
    for (int e4 = 0; e4 < 128; e4++) {
        float4 w = W4[e4 * SELD + k];
#pragma unroll
        for (int p = 0; p < 19; p++) {
            // x = [h(p) | h(p+1)] is contiguous in hl: x4[e4] == h4[p*64 + e4]
            float4 x = h4[p * 64 + e4];
            acc[p] += x.x * w.x + x.y * w.y + x.z * w.z + x.w * w.w;
        }
    }
    float b1 = bs1[k], w2 = Ws2[k];
    int wid = tid >> 6, lane = tid & 63;
#pragma unroll
    for (int p = 0; p < 19; p++) {
        float y = tanhf(acc[p] + b1) * w2;
        for (int off = 32; off >= 1; off >>= 1) y += __shfl_down(y, off);
        if (lane == 0) part[wid][p] = y;
    }
    __syncthreads();
    if (tid < 19) log0[b * 95 + p0 + tid] = part[0][tid] + part[1][tid] + bs2[0];
}

// ---------------- the sequential scan: one block per batch --------------------------------------
__global__ __launch_bounds__(1024) void k_scan(const float* __restrict__ Wc4,
                                               const float* __restrict__ bcomp,
                                               const float* __restrict__ Ws4,
                                               const float* __restrict__ bs1,
                                               const float* __restrict__ Ws2,
                                               const float* __restrict__ bs2,
                                               const float* __restrict__ log0,
                                               float* __restrict__ state,
                                               float* __restrict__ hroot) {
    int b = blockIdx.x;
    int tid = threadIdx.x;
    __shared__ int act[SS];
    __shared__ float logit[SS - 1];
    __shared__ __align__(16) float xcomp[DD];      // [h_l | h_r]
    __shared__ float leftc[HH], rightc[HH];
    __shared__ float a_lds[CK];
    __shared__ __align__(16) float comp_h[HH];
    __shared__ __align__(16) float xsel[2][DD];
    __shared__ float spart[2][4][SELD];
    __shared__ float red[4];
    __shared__ float amax_v[2];
    __shared__ int amax_i[2];
    __shared__ int s_idx;

    float* st = state + (long)b * SS * DD;

    if (tid < SS) act[tid] = tid;
    if (tid < SS - 1) logit[tid] = log0[b * 95 + tid];
    __syncthreads();

    for (int t = 0; t < SS - 1; t++) {
        int n = SS - t;
        // ---- (1) argmax over logit[0..n-2], numpy first-max semantics ----
        if (tid < 128) {
            int p = tid;
            float v = (p < n - 1) ? logit[p] : -3.0e38f;
            int i = p;
#pragma unroll
            for (int off = 1; off < 64; off <<= 1) {
                float ov = __shfl_xor(v, off);
                int oi = __shfl_xor(i, off);
                if (ov > v || (ov == v && oi < i)) { v = ov; i = oi; }
            }
            if ((tid & 63) == 0) { amax_v[tid >> 6] = v; amax_i[tid >> 6] = i; }
        }
        __syncthreads();
        if (tid == 0) {
            float v0 = amax_v[0], v1 = amax_v[1];
            int i0 = amax_i[0], i1 = amax_i[1];
            s_idx = (v1 > v0 || (v1 == v0 && i1 < i0)) ? i1 : i0;
        }
        __syncthreads();
        int idx = s_idx;
        int l = act[idx], r = act[idx + 1];
        int r2  = (idx + 2 <= n - 1) ? act[idx + 2] : -1;  // old neighbor's neighbor
        int lm1 = (idx >= 1) ? act[idx - 1] : -1;
        bool v0ok = (idx >= 1);
        bool v1ok = (idx <= n - 3);

        // ---- (2) stage left/right ----
        if (tid < 512) {
            int j = tid;
            xcomp[j] = (j < HH) ? st[l * DD + HH + j] : st[r * DD + j];
        } else {
            int j = tid - 512;
            if (j < HH) leftc[j] = st[l * DD + j];
            else        rightc[j - HH] = st[r * DD + (j - HH)];
        }
        __syncthreads();

        // ---- (3) comp pre-activations: a = [h_l|h_r] @ W_comp + b ----
        {
            const float4* W4 = (const float4*)Wc4;
            const float4* x4 = (const float4*)xcomp;
            int k = tid;
            float acc = bcomp[k];
            float acc2 = (tid < 256) ? bcomp[1024 + tid] : 0.f;
#pragma unroll 4
            for (int e4 = 0; e4 < 128; e4++) {
                float4 x = x4[e4];
                float4 w = W4[e4 * CK + k];
                acc += x.x * w.x + x.y * w.y + x.z * w.z + x.w * w.w;
                if (tid < 256) {
                    float4 w2v = W4[e4 * CK + 1024 + tid];
                    acc2 += x.x * w2v.x + x.y * w2v.y + x.z * w2v.z + x.w * w2v.w;
                }
            }
            a_lds[k] = acc;
            if (tid < 256) a_lds[1024 + tid] = acc2;
        }
        // read act/logit shift sources BEFORE they get overwritten
        int pA = -1, tA = 0, pL = -1;
        float tL = 0.f;
        {
            int p = tid;
            if (p >= idx + 1 && p <= n - 2) { pA = p; tA = act[p + 1]; }
            if (p >= idx + 1 && p <= n - 3) { pL = p; tL = logit[p + 1]; }
        }
        __syncthreads();

        // ---- (4) gates; write composed state in place into slot l ----
        if (tid < HH) {
            int j = tid;
            float iv = a_lds[j], fl = a_lds[HH + j], fr = a_lds[2 * HH + j];
            float ov = a_lds[3 * HH + j], gc = a_lds[4 * HH + j];
            float si  = 1.f / (1.f + expf(-iv));
            float sfl = 1.f / (1.f + expf(-fl));
            float sfr = 1.f / (1.f + expf(-fr));
            float so  = 1.f / (1.f + expf(-ov));
            float c = sfl * leftc[j] + sfr * rightc[j] + si * tanhf(gc);
            float h = so * tanhf(c);
            st[l * DD + j] = c;
            st[l * DD + HH + j] = h;
            comp_h[j] = h;
        }
        __syncthreads();

        // ---- (5) apply shifts; stage inputs for the 2 refreshed pairs ----
        if (pA >= 0) act[pA] = tA;
        if (pL >= 0) logit[pL] = tL;
        if (tid < 512) {
            int j = tid;
            if (v0ok) xsel[0][j] = (j < HH) ? st[lm1 * DD + HH + j] : comp_h[j - HH];
        } else {
            int j = tid - 512;
            if (v1ok) xsel[1][j] = (j < HH) ? comp_h[j] : st[r2 * DD + HH + (j - HH)];
        }
        __syncthreads();

        // ---- (6) recompute the 2 affected logits (4-way K split) ----
        {
            int q = tid >> 9, sub = (tid >> 7) & 3, k = tid & 127;
            bool valid = (q == 0) ? v0ok : v1ok;
            float acc = 0.f;
            if (valid) {
                const float4* W4 = (const float4*)Ws4;
                const float4* x4 = (const float4*)&xsel[q][0];
#pragma unroll 4
                for (int e4 = sub * 32; e4 < sub * 32 + 32; e4++) {
                    float4 w = W4[e4 * SELD + k];
                    float4 x = x4[e4];
                    acc += x.x * w.x + x.y * w.y + x.z * w.z + x.w * w.w;
                }
            }
            spart[q][sub][k] = acc;
        }
        __syncthreads();
        if (tid < 256) {
            int q = tid >> 7, k = tid & 127;
            bool valid = (q == 0) ? v0ok : v1ok;
            float y = 0.f;
            if (valid) {
                float s = spart[q][0][k] + spart[q][1][k] + spart[q][2][k] + spart[q][3][k] + bs1[k];
                y = tanhf(s) * Ws2[k];
            }
            for (int off = 32; off >= 1; off >>= 1) y += __shfl_down(y, off);
            if ((tid & 63) == 0) red[tid >> 6] = y;
        }
        __syncthreads();
        if (tid == 0) {
            if (v0ok) logit[idx - 1] = red[0] + red[1] + bs2[0];
            if (v1ok) logit[idx]     = red[2] + red[3] + bs2[0];
        }
        __syncthreads();
    }
    if (tid < HH) hroot[b * HH + tid] = st[act[0] * DD + HH + tid];
}

// ---------------- final MLP head ----------------------------------------------------------------
__global__ __launch_bounds__(256) void k_mlp(const float* __restrict__ hroot,
                                             const float* __restrict__ Wm1, const float* __restrict__ bm1,
                                             const float* __restrict__ Wm2, const float* __restrict__ bm2,
                                             const float* __restrict__ Wout, const float* __restrict__ bout,
                                             float* __restrict__ out) {
    int b = blockIdx.x, tid = threadIdx.x;
    __shared__ float x0[HH];
    __shared__ float x1[MLPD];
    __shared__ float x2[MLPD];
    __shared__ float red3[3][256];
    if (tid < HH) x0[tid] = hroot[b * HH + tid];
    __syncthreads();
    {
        float a0 = bm1[tid], a1 = bm1[256 + tid], a2 = bm1[512 + tid], a3 = bm1[768 + tid];
        for (int e = 0; e < HH; e++) {
            float x = x0[e];
            a0 += x * Wm1[e * MLPD + tid];
            a1 += x * Wm1[e * MLPD + 256 + tid];
            a2 += x * Wm1[e * MLPD + 512 + tid];
            a3 += x * Wm1[e * MLPD + 768 + tid];
        }
        x1[tid] = fmaxf(a0, 0.f); x1[256 + tid] = fmaxf(a1, 0.f);
        x1[512 + tid] = fmaxf(a2, 0.f); x1[768 + tid] = fmaxf(a3, 0.f);
    }
    __syncthreads();
    {
        float a0 = bm2[tid], a1 = bm2[256 + tid], a2 = bm2[512 + tid], a3 = bm2[768 + tid];
        for (int e = 0; e < MLPD; e++) {
            float x = x1[e];
            a0 += x * Wm2[e * MLPD + tid];
            a1 += x * Wm2[e * MLPD + 256 + tid];
            a2 += x * Wm2[e * MLPD + 512 + tid];
            a3 += x * Wm2[e * MLPD + 768 + tid];
        }
        x2[tid] = fmaxf(a0, 0.f); x2[256 + tid] = fmaxf(a1, 0.f);
        x2[512 + tid] = fmaxf(a2, 0.f); x2[768 + tid] = fmaxf(a3, 0.f);
    }
    __syncthreads();
    {
        float p0 = 0.f, p1 = 0.f, p2 = 0.f;
        for (int e = tid; e < MLPD; e += 256) {
            float x = x2[e];
            p0 += x * Wout[e * NCLS + 0];
            p1 += x * Wout[e * NCLS + 1];
            p2 += x * Wout[e * NCLS + 2];
        }
        red3[0][tid] = p0; red3[1][tid] = p1; red3[2][tid] = p2;
        __syncthreads();
        for (int sdd = 128; sdd >= 1; sdd >>= 1) {
            if (tid < sdd) {
                red3[0][tid] += red3[0][tid + sdd];
                red3[1][tid] += red3[1][tid + sdd];
                red3[2][tid] += red3[2][tid + sdd];
            }
            __syncthreads();
        }
        if (tid < NCLS) out[b * NCLS + tid] = red3[tid][0] + bout[tid];
    }
}

extern "C" void kernel_launch(void* const* d_in, const int* in_sizes, int n_in,
                              void* d_out, int out_size, void* d_ws, size_t ws_size,
                              hipStream_t stream) {
    const int*   sent  = (const int*)d_in[0];
    // d_in[1] = transitions: unused by the reference
    const float* emb   = (const float*)d_in[2];
    const float* Wenc  = (const float*)d_in[3];
    const float* benc  = (const float*)d_in[4];
    const float* Wcomp = (const float*)d_in[5];
    const float* bcomp = (const float*)d_in[6];
    const float* Wsel1 = (const float*)d_in[7];
    const float* bs1   = (const float*)d_in[8];
    const float* Ws2   = (const float*)d_in[9];
    const float* bs2   = (const float*)d_in[10];
    const float* Wm1   = (const float*)d_in[11];
    const float* bm1   = (const float*)d_in[12];
    const float* Wm2   = (const float*)d_in[13];
    const float* bm2   = (const float*)d_in[14];
    const float* Wout  = (const float*)d_in[15];
    const float* bout  = (const float*)d_in[16];
    float* out = (float*)d_out;

    float* ws    = (float*)d_ws;
    float* state = ws;                                  // 64*96*512   = 3,145,728 f32
    float* Wc4   = ws + 3145728;                        // 128*1280*4  =   655,360 f32
    float* Ws14  = ws + 3145728 + 655360;               // 128*128*4   =    65,536 f32
    float* log0  = ws + 3866624;                        // 64*95       =     6,080 f32
    float* hroot = ws + 3872704;                        // 64*256      =    16,384 f32

    k_trans_comp<<<dim3(128), dim3(256), 0, stream>>>(Wcomp, Wc4);
    k_trans_sel<<<dim3(128), dim3(128), 0, stream>>>(Wsel1, Ws14);
    k_encode<<<dim3(NB * 3), dim3(512), 0, stream>>>(sent, emb, Wenc, benc, state);
    k_logits0<<<dim3(NB * 5), dim3(128), 0, stream>>>(state, Ws14, bs1, Ws2, bs2, log0);
    k_scan<<<dim3(NB), dim3(1024), 0, stream>>>(Wc4, bcomp, Ws14, bs1, Ws2, bs2, log0, state, hroot);
    k_mlp<<<dim3(NB), dim3(256), 0, stream>>>(hroot, Wm1, bm1, Wm2, bm2, Wout, bout, out);
}